// Round 3
// baseline (419.976 us; speedup 1.0000x reference)
//
#include <hip/hip_runtime.h>

#define NLOC  10
#define NGI   13
#define NPAIR 55

// pn[(i*10+j)*13 + g] = n[i,g] * n[j,g] / dt   (full 100x13 table, 5.2 KB in ws)
__global__ void prodn_kernel(const float* __restrict__ nmat,
                             const float* __restrict__ dtp,
                             float* __restrict__ pn) {
    int idx = blockIdx.x * blockDim.x + threadIdx.x;
    if (idx >= NLOC * NLOC * NGI) return;
    int g  = idx % NGI;
    int ij = idx / NGI;
    int i  = ij / NLOC, j = ij % NLOC;
    pn[idx] = nmat[i * NGI + g] * nmat[j * NGI + g] / dtp[0];
}

__device__ __forceinline__ constexpr int pidx(int i, int j) {
    int lo = i < j ? i : j, hi = i < j ? j : i;
    return lo * NLOC - (lo * (lo - 1)) / 2 + (hi - lo);
}

// All register arrays <= 55 elements, scalar compile-time indexed -> full
// SROA/promotion. Peak live ~115 VGPR: acc[55] + chunk rows[40] + s[13] + addr.
__global__ __launch_bounds__(256) void fem_kernel(
    const float* __restrict__ r0_in,
    const float* __restrict__ c_i,
    const float* __restrict__ c_n,
    const float* __restrict__ kp,
    const float* __restrict__ nx,
    const float* __restrict__ detwei,
    const float* __restrict__ pn,
    float* __restrict__ out,
    int nele)
{
    int e = blockIdx.x * blockDim.x + threadIdx.x;
    if (e >= nele) return;

    const float kk = kp[0];

    float dw[NGI], s[NGI];
    {
        const float* dwp = detwei + (size_t)e * NGI;
        #pragma unroll
        for (int g = 0; g < NGI; ++g) dw[g] = dwp[g];
        #pragma unroll
        for (int g = 0; g < NGI; ++g) s[g] = sqrtf(dw[g]);
    }

    float acc[NPAIR];
    #pragma unroll
    for (int p = 0; p < NPAIR; ++p) acc[p] = 0.0f;

    const float* base = nx + (size_t)e * (2 * NLOC * NGI);

    // g-chunks {0..3},{4..7},{8..11},{12} per spatial dim: only 40 row floats
    // live at a time instead of 130.
    #pragma unroll
    for (int d = 0; d < 2; ++d) {
        #pragma unroll
        for (int c = 0; c < 3; ++c) {
            float r[NLOC][4];
            #pragma unroll
            for (int l = 0; l < NLOC; ++l)
                #pragma unroll
                for (int q = 0; q < 4; ++q)
                    r[l][q] = base[d * 130 + l * NGI + c * 4 + q] * s[c * 4 + q];
            #pragma unroll
            for (int i = 0; i < NLOC; ++i)
                #pragma unroll
                for (int j = i; j < NLOC; ++j) {
                    float a = acc[pidx(i, j)];
                    #pragma unroll
                    for (int q = 0; q < 4; ++q)
                        a = fmaf(r[i][q], r[j][q], a);
                    acc[pidx(i, j)] = a;
                }
        }
        {   // tail chunk: g = 12
            float r1[NLOC];
            #pragma unroll
            for (int l = 0; l < NLOC; ++l)
                r1[l] = base[d * 130 + l * NGI + 12] * s[12];
            #pragma unroll
            for (int i = 0; i < NLOC; ++i)
                #pragma unroll
                for (int j = i; j < NLOC; ++j)
                    acc[pidx(i, j)] = fmaf(r1[i], r1[j], acc[pidx(i, j)]);
        }
    }

    // ---------------- epilogue: row-by-row, no big arrays ----------------
    float ci[NLOC], cn[NLOC], rr[NLOC];
    {
        const float2* p2 = reinterpret_cast<const float2*>(c_i) + (size_t)e * 5;
        #pragma unroll
        for (int q = 0; q < 5; ++q) { float2 v = p2[q]; ci[2*q] = v.x; ci[2*q+1] = v.y; }
    }
    {
        const float2* p2 = reinterpret_cast<const float2*>(c_n) + (size_t)e * 5;
        #pragma unroll
        for (int q = 0; q < 5; ++q) { float2 v = p2[q]; cn[2*q] = v.x; cn[2*q+1] = v.y; }
    }
    {
        const float2* p2 = reinterpret_cast<const float2*>(r0_in) + (size_t)e * 5;
        #pragma unroll
        for (int q = 0; q < 5; ++q) { float2 v = p2[q]; rr[2*q] = v.x; rr[2*q+1] = v.y; }
    }

    float* out_bd = out + (size_t)e * 100;
    float* out_dg = out + (size_t)nele * 100 + (size_t)e * NLOC;
    float* out_r0 = out + (size_t)nele * 110 + (size_t)e * NLOC;

    #pragma unroll
    for (int i = 0; i < NLOC; ++i) {
        float row[NLOC];
        #pragma unroll
        for (int j = 0; j < NLOC; ++j) {
            // nndt = sum_g n_i[g]*n_j[g]/dt * detwei[e,g] — pn reads are
            // wave-uniform (same addr all lanes), table stays in L1.
            const float* pnij = pn + (i * NLOC + j) * NGI;
            float nndt = 0.0f;
            #pragma unroll
            for (int g = 0; g < NGI; ++g)
                nndt = fmaf(pnij[g], dw[g], nndt);
            float A = fmaf(acc[pidx(i, j)], kk, nndt);
            row[j] = A;
            rr[i]  = fmaf(nndt, cn[j], rr[i]);
            rr[i]  = fmaf(-A, ci[j], rr[i]);
        }
        float2* orow = reinterpret_cast<float2*>(out_bd + i * NLOC);  // 8B aligned
        #pragma unroll
        for (int q = 0; q < 5; ++q)
            orow[q] = make_float2(row[2*q], row[2*q+1]);
        out_dg[i] = row[i];
    }
    {
        float2* orp = reinterpret_cast<float2*>(out_r0);
        #pragma unroll
        for (int q = 0; q < 5; ++q)
            orp[q] = make_float2(rr[2*q], rr[2*q+1]);
    }
}

extern "C" void kernel_launch(void* const* d_in, const int* in_sizes, int n_in,
                              void* d_out, int out_size, void* d_ws, size_t ws_size,
                              hipStream_t stream) {
    const float* r0   = (const float*)d_in[0];
    const float* ci   = (const float*)d_in[1];
    const float* cn   = (const float*)d_in[2];
    const float* k    = (const float*)d_in[3];
    const float* dt   = (const float*)d_in[4];
    const float* nmat = (const float*)d_in[5];
    const float* nx   = (const float*)d_in[6];
    const float* dw   = (const float*)d_in[7];
    int nele = in_sizes[7] / NGI;

    float* pn = (float*)d_ws;   // 1300 floats
    prodn_kernel<<<(NLOC * NLOC * NGI + 127) / 128, 128, 0, stream>>>(nmat, dt, pn);

    int nb = (nele + 255) / 256;
    fem_kernel<<<nb, 256, 0, stream>>>(r0, ci, cn, k, nx, dw, pn,
                                       (float*)d_out, nele);
}